// Round 13
// baseline (570.210 us; speedup 1.0000x reference)
//
#include <hip/hip_runtime.h>
#include <hip/hip_bf16.h>
#include <math.h>

#define DIM 1024
#define NB  4096      // B
#define N2  8192      // 2B
#define NJOBS 1056    // Σ_{a=0}^{31}(64-2a): tiles (a,v), v>=2a
#define PS  96        // partials stride: 64 col-tile slots + 32 colsum slots

typedef float f32x16 __attribute__((ext_vector_type(16)));
typedef int   i32x4  __attribute__((ext_vector_type(4)));
typedef int   i32x8  __attribute__((ext_vector_type(8)));

__device__ __forceinline__ void gload_lds16(const unsigned char* g, unsigned char* l) {
    __builtin_amdgcn_global_load_lds((__attribute__((address_space(1))) void*)(g),
                                     (__attribute__((address_space(3))) void*)(l),
                                     16, 0, 0);
}

// fp8 e4m3fn encode, round-to-nearest-even (manual fallback)
__device__ __forceinline__ unsigned char to_fp8(float x) {
    unsigned int u = __float_as_uint(x);
    unsigned char s = (unsigned char)((u >> 24) & 0x80);
    int e = (int)((u >> 23) & 0xFF) - 127;
    unsigned int m = u & 0x7FFFFF;
    if (e >= -6) {
        if (e > 8) return s | 0x7E;
        unsigned int keep = m >> 20;
        unsigned int rest = m & 0xFFFFF;
        if (rest > 0x80000u || (rest == 0x80000u && (keep & 1))) keep++;
        unsigned int v = ((unsigned int)(e + 7) << 3) + keep;
        if (v >= 0x7F) v = 0x7E;
        return s | (unsigned char)v;
    }
    if (e < -10) return s;
    int drop = 14 - e;
    unsigned int sig = 0x800000u | m;
    unsigned int keep = sig >> drop;
    unsigned int rem  = sig & ((1u << drop) - 1u);
    unsigned int half = 1u << (drop - 1);
    if (rem > half || (rem == half && (keep & 1))) keep++;
    return s | (unsigned char)keep;
}

__device__ __forceinline__ unsigned int pk4_fp8(float a, float b, float c, float d) {
#if __has_builtin(__builtin_amdgcn_cvt_pk_fp8_f32)
    unsigned int q = 0;
    q = (unsigned int)__builtin_amdgcn_cvt_pk_fp8_f32(a, b, (int)q, false);
    q = (unsigned int)__builtin_amdgcn_cvt_pk_fp8_f32(c, d, (int)q, true);
    return q;
#else
    union { unsigned int u; unsigned char cc[4]; } q;
    q.cc[0] = to_fp8(a); q.cc[1] = to_fp8(b); q.cc[2] = to_fp8(c); q.cc[3] = to_fp8(d);
    return q.u;
#endif
}

// ---------------- Kernel 1: normalize rows, emit fp8 z (k-interleaved), pos --
// Column permutation within each 64-block (row-independent): any fixed K-perm
// applied to BOTH MFMA operands cancels in the dot product.
__global__ __launch_bounds__(256) void norm_kernel(
    const float* __restrict__ p1, const float* __restrict__ p2,
    unsigned char* __restrict__ zq, float* __restrict__ pos)
{
    const int r = blockIdx.x;
    const int t = threadIdx.x;
    const float4 x1 = ((const float4*)(p1 + (size_t)r * DIM))[t];
    const float4 x2 = ((const float4*)(p2 + (size_t)r * DIM))[t];
    float s1  = x1.x*x1.x + x1.y*x1.y + x1.z*x1.z + x1.w*x1.w;
    float s2  = x2.x*x2.x + x2.y*x2.y + x2.z*x2.z + x2.w*x2.w;
    float s12 = x1.x*x2.x + x1.y*x2.y + x1.z*x2.z + x1.w*x2.w;
#pragma unroll
    for (int off = 1; off < 64; off <<= 1) {
        s1  += __shfl_xor(s1,  off);
        s2  += __shfl_xor(s2,  off);
        s12 += __shfl_xor(s12, off);
    }
    __shared__ float ls[3][4];
    const int wid = t >> 6;
    if ((t & 63) == 0) { ls[0][wid] = s1; ls[1][wid] = s2; ls[2][wid] = s12; }
    __syncthreads();
    s1  = ls[0][0] + ls[0][1] + ls[0][2] + ls[0][3];
    s2  = ls[1][0] + ls[1][1] + ls[1][2] + ls[1][3];
    s12 = ls[2][0] + ls[2][1] + ls[2][2] + ls[2][3];
    const float rn1 = 1.0f / fmaxf(sqrtf(s1), 1e-12f);
    const float rn2 = 1.0f / fmaxf(sqrtf(s2), 1e-12f);
    if (t == 0) pos[r] = s12 * rn1 * rn2;

    const int j0 = (t << 2) & 63;       // col within 64-block
    const int kb = t >> 4;              // 64-block index
    const int pb = (j0 < 32) ? (((j0 >> 3) << 4) + (j0 & 7))
                             : ((((j0 - 32) >> 3) << 4) + 8 + ((j0 - 32) & 7));
    const size_t off8 = (size_t)kb * 64 + pb;
    *(unsigned int*)(zq + (size_t)r * DIM + off8) =
        pk4_fp8(x1.x * rn1, x1.y * rn1, x1.z * rn1, x1.w * rn1);
    *(unsigned int*)(zq + (size_t)(NB + r) * DIM + off8) =
        pk4_fp8(x2.x * rn2, x2.y * rn2, x2.z * rn2, x2.w * rn2);
}

// ------- Kernel 2: 256x128 MX-fp8 symmetric z.z^T, mfma_scale 32x32x64 ------
// Tile (a,v): A rows [256a,+256), B cols [128v,+128), v>=2a. 8 waves (4x2),
// per-wave 64x64 via 2x2 quadrants of 32x32, acc f32x16 each. Scale=127
// (E8M0 => 1.0, exact). Per-wave unit predicates are wave-uniform:
// ur=2a+(wr>>1), uc=v. ds_read: 2 b128 per fragment (logical granules 2h,2h+1
// un-swizzled per-row) -> rows 0-7 x slots cover all 32 banks once each.
__global__ __launch_bounds__(512, 4) void sim_kernel(
    const unsigned char* __restrict__ zq,
    float* __restrict__ partials,    // [N2][PS], zeroed before launch
    float* __restrict__ lup)         // [NJOBS]
{
    __shared__ __align__(16) unsigned char bufA[2][256 * 64]; // 32 KB
    __shared__ __align__(16) unsigned char bufB[2][128 * 64]; // 16 KB

    const int t    = threadIdx.x;
    const int lane = t & 63;
    const int wid  = t >> 6;       // 0..7
    const int wr   = wid >> 1;     // 0..3 (64-row strip of 256)
    const int wc   = wid & 1;      // 0..1 (64-col strip of 128)

    const int bid = blockIdx.x;
    const int job = (bid & 7) * (NJOBS / 8) + (bid >> 3);   // bijective XCD chunk
    int a = 0;                                   // start(a) = a*(65-a)
    while ((a + 1) * (64 - a) <= job) ++a;
    const int v = 2 * a + (job - a * (65 - a));
    const int row0 = a << 8;
    const int col0 = v << 7;

    const int colf = lane & 31;    // fragment row (A) / col (B) within 32
    const int hi   = lane >> 5;    // k-half 0/1
    const int rc   = (colf >> 1) & 3;                 // bank-swizzle row class
    const int sl0  = (((hi << 1) | 0) ^ rc) << 4;     // swizzled granule bytes
    const int sl1  = (((hi << 1) | 1) ^ rc) << 4;
    const int aO0  = ((wr << 6) + colf) << 6;         // quadrant m=0 row base
    const int aO1  = ((wr << 6) + 32 + colf) << 6;    // m=1
    const int bO0  = ((wc << 6) + colf) << 6;         // n=0
    const int bO1  = ((wc << 6) + 32 + colf) << 6;    // n=1

    // staging: 24 chunks of 16 rows x 64B (A: 0-15, B: 16-23), 3 per wave;
    // lane: row l>>2, LDS slot l&3, global granule (l&3)^((l>>3)&3) (involution)
    const int srow = lane >> 2;
    const int sgr  = (((lane & 3) ^ ((lane >> 3) & 3)) << 4);

#define STAGE(bsel, ktv) do { \
    _Pragma("unroll") \
    for (int c = 0; c < 3; ++c) { \
        const int ch  = wid * 3 + c; \
        const int isB = ch >> 4; \
        const int chl = ch & 15; \
        const unsigned char* src = zq + (size_t)((isB ? col0 : row0) + (chl << 4) + srow) * DIM \
                                      + (ktv) * 64 + sgr; \
        gload_lds16(src, (isB ? &bufB[bsel][chl << 10] : &bufA[bsel][chl << 10])); \
    } \
} while (0)

#define RD8(dst, base, off) do { \
    i32x4 lo_ = *(const i32x4*)((base) + (off) + sl0); \
    i32x4 hi_ = *(const i32x4*)((base) + (off) + sl1); \
    dst = __builtin_shufflevector(lo_, hi_, 0, 1, 2, 3, 4, 5, 6, 7); \
} while (0)

    f32x16 acc00 = {}, acc01 = {}, acc10 = {}, acc11 = {};

    STAGE(0, 0);
    __syncthreads();

#pragma unroll
    for (int kt = 0; kt < 16; ++kt) {
        const int cur = kt & 1;
        if (kt < 15) STAGE(cur ^ 1, kt + 1);
        const unsigned char* Ab = &bufA[cur][0];
        const unsigned char* Bb = &bufB[cur][0];
        i32x8 a0, a1, b0, b1;
        RD8(b0, Bb, bO0); RD8(b1, Bb, bO1);
        RD8(a0, Ab, aO0); RD8(a1, Ab, aO1);
        acc00 = __builtin_amdgcn_mfma_scale_f32_32x32x64_f8f6f4(a0, b0, acc00, 0, 0, 0, 127, 0, 127);
        acc01 = __builtin_amdgcn_mfma_scale_f32_32x32x64_f8f6f4(a0, b1, acc01, 0, 0, 0, 127, 0, 127);
        acc10 = __builtin_amdgcn_mfma_scale_f32_32x32x64_f8f6f4(a1, b0, acc10, 0, 0, 0, 127, 0, 127);
        acc11 = __builtin_amdgcn_mfma_scale_f32_32x32x64_f8f6f4(a1, b1, acc11, 0, 0, 0, 127, 0, 127);
        __syncthreads();
    }
#undef RD8
#undef STAGE

    // ---- epilogue: 32x32 C/D layout col=lane&31, row=(reg&3)+8(reg>>2)+4hi --
    float* rsum2 = (float*)&bufA[0][0];     // [256][2] per-(row,wc)
    float* csum4 = rsum2 + 512;             // [128][4] per-(col,wr)
    float* lured = csum4 + 512;             // [8]

    const int  ur   = 2 * a + (wr >> 1);    // wave-uniform row unit
    const bool rowP = (ur <= v);
    const bool colP = (ur <  v);

    float lu = 0.0f;
    float cs[2] = {0.0f, 0.0f};
#pragma unroll
    for (int m = 0; m < 2; ++m) {
        const int rbase = row0 + (wr << 6) + (m << 5);
        const int rblk  = rbase >> 11;
        float rs[16] = {};
#pragma unroll
        for (int n = 0; n < 2; ++n) {
            const int  cbase = col0 + (wc << 6) + (n << 5);
            const bool dq    = (rbase == cbase);
            const bool inreg = ((cbase >> 11) == rblk) && (rblk < 2);
            const bool abv   = (cbase > rbase);
            const f32x16 d = m ? (n ? acc11 : acc10) : (n ? acc01 : acc00);
#pragma unroll
            for (int r = 0; r < 16; ++r) {
                const int rw = (r & 3) + ((r >> 2) << 3) + (hi << 2);
                const float s = d[r];
                float e = exp2f(14.4269504f * s);
                if (dq) e = (colf == rw) ? 0.0f : e;
                if (rowP) rs[r] += e;
                if (colP) cs[n] += e;
                if (inreg && (abv || (dq && (colf > rw)))) {
                    const float d2 = fmaxf(2.0f - 2.0f * s, 0.0f);
                    lu += exp2f(-2.88539008f * d2);
                }
            }
        }
#pragma unroll
        for (int off = 1; off < 32; off <<= 1) {
#pragma unroll
            for (int r = 0; r < 16; ++r) rs[r] += __shfl_xor(rs[r], off);
        }
        if (colf == 0) {
#pragma unroll
            for (int r = 0; r < 16; ++r) {
                const int rw = (r & 3) + ((r >> 2) << 3) + (hi << 2);
                rsum2[((wr << 6) + (m << 5) + rw) * 2 + wc] = rs[r];
            }
        }
    }
#pragma unroll
    for (int n = 0; n < 2; ++n) cs[n] += __shfl_xor(cs[n], 32);
    if (hi == 0) {
#pragma unroll
        for (int n = 0; n < 2; ++n)
            csum4[((wc << 6) + (n << 5) + colf) * 4 + wr] = cs[n];
    }
#pragma unroll
    for (int off = 1; off < 64; off <<= 1) lu += __shfl_xor(lu, off);
    if (lane == 0) lured[wid] = lu;
    __syncthreads();

    if (t == 0) {
        float s = 0.0f;
#pragma unroll
        for (int w = 0; w < 8; ++w) s += lured[w];
        lup[job] = s;
    }
    if (t < 256) {
        partials[(size_t)(row0 + t) * PS + v] = rsum2[t * 2] + rsum2[t * 2 + 1];
    } else if (t < 384) {
        const int j2 = t - 256;
        const float* p = csum4 + j2 * 4;
        partials[(size_t)(col0 + j2) * PS + 64 + a] = ((p[0] + p[1]) + p[2]) + p[3];
    }
}

// --------- Kernel 3a: per-row denom -> log, 128 rows per block --------------
__global__ __launch_bounds__(128) void logred_kernel(
    const float* __restrict__ partials, double* __restrict__ red_log)
{
    const int t   = threadIdx.x;
    const int row = blockIdx.x * 128 + t;
    const float* p = partials + (size_t)row * PS;
    float dsum = 0.0f;
#pragma unroll
    for (int i = 0; i < PS; ++i) dsum += p[i];
    double l = log((double)dsum);
    __shared__ double sd[128];
    sd[t] = l;
    __syncthreads();
    for (int s = 64; s > 0; s >>= 1) {
        if (t < s) sd[t] += sd[t + s];
        __syncthreads();
    }
    if (t == 0) red_log[blockIdx.x] = sd[0];
}

// --------- Kernel 3b: final scalars --------------------------------------
__global__ __launch_bounds__(256) void final_kernel(
    const double* __restrict__ red_log, const float* __restrict__ pos,
    const float* __restrict__ lup, float* __restrict__ out)
{
    const int t = threadIdx.x;
    double dlog = 0.0, dpos = 0.0, ds1 = 0.0, ds2 = 0.0;
    if (t < 64) dlog = red_log[t];
    for (int i = t; i < NB; i += 256) dpos += (double)pos[i];
    for (int i = t; i < NJOBS; i += 256) {
        int a = 0;
        while ((a + 1) * (64 - a) <= i) ++a;
        const int v = 2 * a + (i - a * (65 - a));
        const double val = (double)lup[i];
        if (a < 8 && v < 16) ds1 += val;                       // z_i[:2048] block
        else if (a >= 8 && a < 16 && v >= 16 && v < 32) ds2 += val; // z_i[2048:]
    }
    __shared__ double sd[4][256];
    sd[0][t] = dlog; sd[1][t] = dpos; sd[2][t] = ds1; sd[3][t] = ds2;
    __syncthreads();
    for (int s = 128; s > 0; s >>= 1) {
        if (t < s) {
            sd[0][t] += sd[0][t + s]; sd[1][t] += sd[1][t + s];
            sd[2][t] += sd[2][t + s]; sd[3][t] += sd[3][t + s];
        }
        __syncthreads();
    }
    if (t == 0) {
        const double mean_pos = sd[1][0] / (double)NB;
        const double loss   = sd[0][0] / (double)N2 - mean_pos * 10.0;   // /TEMP
        const double lalign = 2.0 - 2.0 * mean_pos;
        const double C      = 2048.0 * 2047.0 * 0.5;
        const double lunif  = 0.5 * (log(sd[2][0] / C) + log(sd[3][0] / C));
        out[0] = (float)loss;
        out[1] = (float)lalign;
        out[2] = (float)lunif;
    }
}

extern "C" void kernel_launch(void* const* d_in, const int* in_sizes, int n_in,
                              void* d_out, int out_size, void* d_ws, size_t ws_size,
                              hipStream_t stream) {
    const float* p1 = (const float*)d_in[0];
    const float* p2 = (const float*)d_in[1];
    float* out = (float*)d_out;

    char* ws = (char*)d_ws;
    unsigned char* zq = (unsigned char*)ws;                               // 8 MB
    float*  partials  = (float*)(ws + ((size_t)8 << 20));                 // 3 MB [8192][96]
    float*  pos       = (float*)(ws + ((size_t)12 << 20));                // 16 KB
    float*  lup       = (float*)(ws + ((size_t)12 << 20) + 16384);        // ~4.2 KB
    double* red_log   = (double*)(ws + ((size_t)12 << 20) + 24576);       // 512 B

    hipMemsetAsync(partials, 0, (size_t)N2 * PS * sizeof(float), stream);
    hipLaunchKernelGGL(norm_kernel,   dim3(NB),    dim3(256), 0, stream, p1, p2, zq, pos);
    hipLaunchKernelGGL(sim_kernel,    dim3(NJOBS), dim3(512), 0, stream, zq, partials, lup);
    hipLaunchKernelGGL(logred_kernel, dim3(64),    dim3(128), 0, stream, partials, red_log);
    hipLaunchKernelGGL(final_kernel,  dim3(1),     dim3(256), 0, stream, red_log, pos, lup, out);
}

// Round 14
// 333.785 us; speedup vs baseline: 1.7083x; 1.7083x over previous
//
#include <hip/hip_runtime.h>
#include <hip/hip_bf16.h>
#include <math.h>

#define DIM 1024
#define NB  4096      // B
#define N2  8192      // 2B
#define NJOBS 1056    // Σ_{a=0}^{31}(64-2a): tiles (a,v), v>=2a
#define PS  96        // partials stride: 64 col-tile slots + 32 colsum slots

typedef float f32x16 __attribute__((ext_vector_type(16)));
typedef int   i32x4  __attribute__((ext_vector_type(4)));
typedef int   i32x8  __attribute__((ext_vector_type(8)));

__device__ __forceinline__ void gload_lds16(const unsigned char* g, unsigned char* l) {
    __builtin_amdgcn_global_load_lds((__attribute__((address_space(1))) void*)(g),
                                     (__attribute__((address_space(3))) void*)(l),
                                     16, 0, 0);
}

// fp8 e4m3fn encode, round-to-nearest-even (manual fallback)
__device__ __forceinline__ unsigned char to_fp8(float x) {
    unsigned int u = __float_as_uint(x);
    unsigned char s = (unsigned char)((u >> 24) & 0x80);
    int e = (int)((u >> 23) & 0xFF) - 127;
    unsigned int m = u & 0x7FFFFF;
    if (e >= -6) {
        if (e > 8) return s | 0x7E;
        unsigned int keep = m >> 20;
        unsigned int rest = m & 0xFFFFF;
        if (rest > 0x80000u || (rest == 0x80000u && (keep & 1))) keep++;
        unsigned int v = ((unsigned int)(e + 7) << 3) + keep;
        if (v >= 0x7F) v = 0x7E;
        return s | (unsigned char)v;
    }
    if (e < -10) return s;
    int drop = 14 - e;
    unsigned int sig = 0x800000u | m;
    unsigned int keep = sig >> drop;
    unsigned int rem  = sig & ((1u << drop) - 1u);
    unsigned int half = 1u << (drop - 1);
    if (rem > half || (rem == half && (keep & 1))) keep++;
    return s | (unsigned char)keep;
}

__device__ __forceinline__ unsigned int pk4_fp8(float a, float b, float c, float d) {
#if __has_builtin(__builtin_amdgcn_cvt_pk_fp8_f32)
    unsigned int q = 0;
    q = (unsigned int)__builtin_amdgcn_cvt_pk_fp8_f32(a, b, (int)q, false);
    q = (unsigned int)__builtin_amdgcn_cvt_pk_fp8_f32(c, d, (int)q, true);
    return q;
#else
    union { unsigned int u; unsigned char cc[4]; } q;
    q.cc[0] = to_fp8(a); q.cc[1] = to_fp8(b); q.cc[2] = to_fp8(c); q.cc[3] = to_fp8(d);
    return q.u;
#endif
}

// ---------------- Kernel 1: normalize rows, emit fp8 z (k-interleaved), pos --
// Column permutation within each 64-block (row-independent): any fixed K-perm
// applied to BOTH MFMA operands cancels in the dot product.
__global__ __launch_bounds__(256) void norm_kernel(
    const float* __restrict__ p1, const float* __restrict__ p2,
    unsigned char* __restrict__ zq, float* __restrict__ pos)
{
    const int r = blockIdx.x;
    const int t = threadIdx.x;
    const float4 x1 = ((const float4*)(p1 + (size_t)r * DIM))[t];
    const float4 x2 = ((const float4*)(p2 + (size_t)r * DIM))[t];
    float s1  = x1.x*x1.x + x1.y*x1.y + x1.z*x1.z + x1.w*x1.w;
    float s2  = x2.x*x2.x + x2.y*x2.y + x2.z*x2.z + x2.w*x2.w;
    float s12 = x1.x*x2.x + x1.y*x2.y + x1.z*x2.z + x1.w*x2.w;
#pragma unroll
    for (int off = 1; off < 64; off <<= 1) {
        s1  += __shfl_xor(s1,  off);
        s2  += __shfl_xor(s2,  off);
        s12 += __shfl_xor(s12, off);
    }
    __shared__ float ls[3][4];
    const int wid = t >> 6;
    if ((t & 63) == 0) { ls[0][wid] = s1; ls[1][wid] = s2; ls[2][wid] = s12; }
    __syncthreads();
    s1  = ls[0][0] + ls[0][1] + ls[0][2] + ls[0][3];
    s2  = ls[1][0] + ls[1][1] + ls[1][2] + ls[1][3];
    s12 = ls[2][0] + ls[2][1] + ls[2][2] + ls[2][3];
    const float rn1 = 1.0f / fmaxf(sqrtf(s1), 1e-12f);
    const float rn2 = 1.0f / fmaxf(sqrtf(s2), 1e-12f);
    if (t == 0) pos[r] = s12 * rn1 * rn2;

    const int j0 = (t << 2) & 63;       // col within 64-block
    const int kb = t >> 4;              // 64-block index
    const int pb = (j0 < 32) ? (((j0 >> 3) << 4) + (j0 & 7))
                             : ((((j0 - 32) >> 3) << 4) + 8 + ((j0 - 32) & 7));
    const size_t off8 = (size_t)kb * 64 + pb;
    *(unsigned int*)(zq + (size_t)r * DIM + off8) =
        pk4_fp8(x1.x * rn1, x1.y * rn1, x1.z * rn1, x1.w * rn1);
    *(unsigned int*)(zq + (size_t)(NB + r) * DIM + off8) =
        pk4_fp8(x2.x * rn2, x2.y * rn2, x2.z * rn2, x2.w * rn2);
}

// ------- Kernel 2: 256x128 MX-fp8 symmetric z.z^T, mfma_scale 32x32x64 ------
// Tile (a,v): A rows [256a,+256), B cols [128v,+128), v>=2a. 8 waves (4x2),
// per-wave 64x64 via 2x2 quadrants of 32x32, acc f32x16 each. Scale=127
// (E8M0 => 1.0, exact). REGISTER BUDGET: launch_bounds(512,2) -> 256 regs;
// (512,4)'s 128-reg budget spilled all four f32x16 accs to scratch
// (R13: 942 MB scratch writes, MfmaUtil 0.06%, 6.7x slower). R12 proved
// 2-block co-residency is neutral, so the occupancy cost is free.
__global__ __launch_bounds__(512, 2) void sim_kernel(
    const unsigned char* __restrict__ zq,
    float* __restrict__ partials,    // [N2][PS], zeroed before launch
    float* __restrict__ lup)         // [NJOBS]
{
    __shared__ __align__(16) unsigned char bufA[2][256 * 64]; // 32 KB
    __shared__ __align__(16) unsigned char bufB[2][128 * 64]; // 16 KB

    const int t    = threadIdx.x;
    const int lane = t & 63;
    const int wid  = t >> 6;       // 0..7
    const int wr   = wid >> 1;     // 0..3 (64-row strip of 256)
    const int wc   = wid & 1;      // 0..1 (64-col strip of 128)

    const int bid = blockIdx.x;
    const int job = (bid & 7) * (NJOBS / 8) + (bid >> 3);   // bijective XCD chunk
    int a = 0;                                   // start(a) = a*(65-a)
    while ((a + 1) * (64 - a) <= job) ++a;
    const int v = 2 * a + (job - a * (65 - a));
    const int row0 = a << 8;
    const int col0 = v << 7;

    const int colf = lane & 31;    // fragment row (A) / col (B) within 32
    const int hi   = lane >> 5;    // k-half 0/1
    const int rc   = (colf >> 1) & 3;                 // bank-swizzle row class
    const int sl0  = (((hi << 1) | 0) ^ rc) << 4;     // swizzled granule bytes
    const int sl1  = (((hi << 1) | 1) ^ rc) << 4;
    const int aO0  = ((wr << 6) + colf) << 6;         // quadrant m=0 row base
    const int aO1  = ((wr << 6) + 32 + colf) << 6;    // m=1
    const int bO0  = ((wc << 6) + colf) << 6;         // n=0
    const int bO1  = ((wc << 6) + 32 + colf) << 6;    // n=1

    // staging: 24 chunks of 16 rows x 64B (A: 0-15, B: 16-23), 3 per wave;
    // lane: row l>>2, LDS slot l&3, global granule (l&3)^((l>>3)&3) (involution)
    const int srow = lane >> 2;
    const int sgr  = (((lane & 3) ^ ((lane >> 3) & 3)) << 4);

#define STAGE(bsel, ktv) do { \
    _Pragma("unroll") \
    for (int c = 0; c < 3; ++c) { \
        const int ch  = wid * 3 + c; \
        const int isB = ch >> 4; \
        const int chl = ch & 15; \
        const unsigned char* src = zq + (size_t)((isB ? col0 : row0) + (chl << 4) + srow) * DIM \
                                      + (ktv) * 64 + sgr; \
        gload_lds16(src, (isB ? &bufB[bsel][chl << 10] : &bufA[bsel][chl << 10])); \
    } \
} while (0)

#define RD8(dst, base, off) do { \
    i32x4 lo_ = *(const i32x4*)((base) + (off) + sl0); \
    i32x4 hi_ = *(const i32x4*)((base) + (off) + sl1); \
    dst = __builtin_shufflevector(lo_, hi_, 0, 1, 2, 3, 4, 5, 6, 7); \
} while (0)

    f32x16 acc00 = {}, acc01 = {}, acc10 = {}, acc11 = {};

    STAGE(0, 0);
    __syncthreads();

#pragma unroll
    for (int kt = 0; kt < 16; ++kt) {
        const int cur = kt & 1;
        if (kt < 15) STAGE(cur ^ 1, kt + 1);
        const unsigned char* Ab = &bufA[cur][0];
        const unsigned char* Bb = &bufB[cur][0];
        i32x8 a0, a1, b0, b1;
        RD8(b0, Bb, bO0); RD8(b1, Bb, bO1);
        RD8(a0, Ab, aO0); RD8(a1, Ab, aO1);
        acc00 = __builtin_amdgcn_mfma_scale_f32_32x32x64_f8f6f4(a0, b0, acc00, 0, 0, 0, 127, 0, 127);
        acc01 = __builtin_amdgcn_mfma_scale_f32_32x32x64_f8f6f4(a0, b1, acc01, 0, 0, 0, 127, 0, 127);
        acc10 = __builtin_amdgcn_mfma_scale_f32_32x32x64_f8f6f4(a1, b0, acc10, 0, 0, 0, 127, 0, 127);
        acc11 = __builtin_amdgcn_mfma_scale_f32_32x32x64_f8f6f4(a1, b1, acc11, 0, 0, 0, 127, 0, 127);
        __syncthreads();
    }
#undef RD8
#undef STAGE

    // ---- epilogue: 32x32 C/D layout col=lane&31, row=(reg&3)+8(reg>>2)+4hi --
    float* rsum2 = (float*)&bufA[0][0];     // [256][2] per-(row,wc)
    float* csum4 = rsum2 + 512;             // [128][4] per-(col,wr)
    float* lured = csum4 + 512;             // [8]

    const int  ur   = 2 * a + (wr >> 1);    // wave-uniform row unit
    const bool rowP = (ur <= v);
    const bool colP = (ur <  v);

    float lu = 0.0f;
    float cs[2] = {0.0f, 0.0f};
#pragma unroll
    for (int m = 0; m < 2; ++m) {
        const int rbase = row0 + (wr << 6) + (m << 5);
        const int rblk  = rbase >> 11;
        float rs[16] = {};
#pragma unroll
        for (int n = 0; n < 2; ++n) {
            const int  cbase = col0 + (wc << 6) + (n << 5);
            const bool dq    = (rbase == cbase);
            const bool inreg = ((cbase >> 11) == rblk) && (rblk < 2);
            const bool abv   = (cbase > rbase);
            const f32x16 d = m ? (n ? acc11 : acc10) : (n ? acc01 : acc00);
#pragma unroll
            for (int r = 0; r < 16; ++r) {
                const int rw = (r & 3) + ((r >> 2) << 3) + (hi << 2);
                const float s = d[r];
                float e = exp2f(14.4269504f * s);
                if (dq) e = (colf == rw) ? 0.0f : e;
                if (rowP) rs[r] += e;
                if (colP) cs[n] += e;
                if (inreg && (abv || (dq && (colf > rw)))) {
                    const float d2 = fmaxf(2.0f - 2.0f * s, 0.0f);
                    lu += exp2f(-2.88539008f * d2);
                }
            }
        }
#pragma unroll
        for (int off = 1; off < 32; off <<= 1) {
#pragma unroll
            for (int r = 0; r < 16; ++r) rs[r] += __shfl_xor(rs[r], off);
        }
        if (colf == 0) {
#pragma unroll
            for (int r = 0; r < 16; ++r) {
                const int rw = (r & 3) + ((r >> 2) << 3) + (hi << 2);
                rsum2[((wr << 6) + (m << 5) + rw) * 2 + wc] = rs[r];
            }
        }
    }
#pragma unroll
    for (int n = 0; n < 2; ++n) cs[n] += __shfl_xor(cs[n], 32);
    if (hi == 0) {
#pragma unroll
        for (int n = 0; n < 2; ++n)
            csum4[((wc << 6) + (n << 5) + colf) * 4 + wr] = cs[n];
    }
#pragma unroll
    for (int off = 1; off < 64; off <<= 1) lu += __shfl_xor(lu, off);
    if (lane == 0) lured[wid] = lu;
    __syncthreads();

    if (t == 0) {
        float s = 0.0f;
#pragma unroll
        for (int w = 0; w < 8; ++w) s += lured[w];
        lup[job] = s;
    }
    if (t < 256) {
        partials[(size_t)(row0 + t) * PS + v] = rsum2[t * 2] + rsum2[t * 2 + 1];
    } else if (t < 384) {
        const int j2 = t - 256;
        const float* p = csum4 + j2 * 4;
        partials[(size_t)(col0 + j2) * PS + 64 + a] = ((p[0] + p[1]) + p[2]) + p[3];
    }
}

// --------- Kernel 3a: per-row denom -> log, 128 rows per block --------------
__global__ __launch_bounds__(128) void logred_kernel(
    const float* __restrict__ partials, double* __restrict__ red_log)
{
    const int t   = threadIdx.x;
    const int row = blockIdx.x * 128 + t;
    const float* p = partials + (size_t)row * PS;
    float dsum = 0.0f;
#pragma unroll
    for (int i = 0; i < PS; ++i) dsum += p[i];
    double l = log((double)dsum);
    __shared__ double sd[128];
    sd[t] = l;
    __syncthreads();
    for (int s = 64; s > 0; s >>= 1) {
        if (t < s) sd[t] += sd[t + s];
        __syncthreads();
    }
    if (t == 0) red_log[blockIdx.x] = sd[0];
}

// --------- Kernel 3b: final scalars --------------------------------------
__global__ __launch_bounds__(256) void final_kernel(
    const double* __restrict__ red_log, const float* __restrict__ pos,
    const float* __restrict__ lup, float* __restrict__ out)
{
    const int t = threadIdx.x;
    double dlog = 0.0, dpos = 0.0, ds1 = 0.0, ds2 = 0.0;
    if (t < 64) dlog = red_log[t];
    for (int i = t; i < NB; i += 256) dpos += (double)pos[i];
    for (int i = t; i < NJOBS; i += 256) {
        int a = 0;
        while ((a + 1) * (64 - a) <= i) ++a;
        const int v = 2 * a + (i - a * (65 - a));
        const double val = (double)lup[i];
        if (a < 8 && v < 16) ds1 += val;                       // z_i[:2048] block
        else if (a >= 8 && a < 16 && v >= 16 && v < 32) ds2 += val; // z_i[2048:]
    }
    __shared__ double sd[4][256];
    sd[0][t] = dlog; sd[1][t] = dpos; sd[2][t] = ds1; sd[3][t] = ds2;
    __syncthreads();
    for (int s = 128; s > 0; s >>= 1) {
        if (t < s) {
            sd[0][t] += sd[0][t + s]; sd[1][t] += sd[1][t + s];
            sd[2][t] += sd[2][t + s]; sd[3][t] += sd[3][t + s];
        }
        __syncthreads();
    }
    if (t == 0) {
        const double mean_pos = sd[1][0] / (double)NB;
        const double loss   = sd[0][0] / (double)N2 - mean_pos * 10.0;   // /TEMP
        const double lalign = 2.0 - 2.0 * mean_pos;
        const double C      = 2048.0 * 2047.0 * 0.5;
        const double lunif  = 0.5 * (log(sd[2][0] / C) + log(sd[3][0] / C));
        out[0] = (float)loss;
        out[1] = (float)lalign;
        out[2] = (float)lunif;
    }
}

extern "C" void kernel_launch(void* const* d_in, const int* in_sizes, int n_in,
                              void* d_out, int out_size, void* d_ws, size_t ws_size,
                              hipStream_t stream) {
    const float* p1 = (const float*)d_in[0];
    const float* p2 = (const float*)d_in[1];
    float* out = (float*)d_out;

    char* ws = (char*)d_ws;
    unsigned char* zq = (unsigned char*)ws;                               // 8 MB
    float*  partials  = (float*)(ws + ((size_t)8 << 20));                 // 3 MB [8192][96]
    float*  pos       = (float*)(ws + ((size_t)12 << 20));                // 16 KB
    float*  lup       = (float*)(ws + ((size_t)12 << 20) + 16384);        // ~4.2 KB
    double* red_log   = (double*)(ws + ((size_t)12 << 20) + 24576);       // 512 B

    hipMemsetAsync(partials, 0, (size_t)N2 * PS * sizeof(float), stream);
    hipLaunchKernelGGL(norm_kernel,   dim3(NB),    dim3(256), 0, stream, p1, p2, zq, pos);
    hipLaunchKernelGGL(sim_kernel,    dim3(NJOBS), dim3(512), 0, stream, zq, partials, lup);
    hipLaunchKernelGGL(logred_kernel, dim3(64),    dim3(128), 0, stream, partials, red_log);
    hipLaunchKernelGGL(final_kernel,  dim3(1),     dim3(256), 0, stream, red_log, pos, lup, out);
}

// Round 15
// 325.556 us; speedup vs baseline: 1.7515x; 1.0253x over previous
//
#include <hip/hip_runtime.h>
#include <hip/hip_bf16.h>
#include <math.h>

#define DIM 1024
#define NB  4096      // B
#define N2  8192      // 2B
#define NJOBS 1056    // Σ_{a=0}^{31}(64-2a): tiles (a,v), v>=2a
#define PS  96        // partials stride: 64 col-tile slots + 32 colsum slots

typedef float f32x16 __attribute__((ext_vector_type(16)));
typedef int   i32x4  __attribute__((ext_vector_type(4)));
typedef int   i32x8  __attribute__((ext_vector_type(8)));

__device__ __forceinline__ void gload_lds16(const unsigned char* g, unsigned char* l) {
    __builtin_amdgcn_global_load_lds((__attribute__((address_space(1))) void*)(g),
                                     (__attribute__((address_space(3))) void*)(l),
                                     16, 0, 0);
}

// fp8 e4m3fn encode, round-to-nearest-even (manual fallback)
__device__ __forceinline__ unsigned char to_fp8(float x) {
    unsigned int u = __float_as_uint(x);
    unsigned char s = (unsigned char)((u >> 24) & 0x80);
    int e = (int)((u >> 23) & 0xFF) - 127;
    unsigned int m = u & 0x7FFFFF;
    if (e >= -6) {
        if (e > 8) return s | 0x7E;
        unsigned int keep = m >> 20;
        unsigned int rest = m & 0xFFFFF;
        if (rest > 0x80000u || (rest == 0x80000u && (keep & 1))) keep++;
        unsigned int v = ((unsigned int)(e + 7) << 3) + keep;
        if (v >= 0x7F) v = 0x7E;
        return s | (unsigned char)v;
    }
    if (e < -10) return s;
    int drop = 14 - e;
    unsigned int sig = 0x800000u | m;
    unsigned int keep = sig >> drop;
    unsigned int rem  = sig & ((1u << drop) - 1u);
    unsigned int half = 1u << (drop - 1);
    if (rem > half || (rem == half && (keep & 1))) keep++;
    return s | (unsigned char)keep;
}

__device__ __forceinline__ unsigned int pk4_fp8(float a, float b, float c, float d) {
#if __has_builtin(__builtin_amdgcn_cvt_pk_fp8_f32)
    unsigned int q = 0;
    q = (unsigned int)__builtin_amdgcn_cvt_pk_fp8_f32(a, b, (int)q, false);
    q = (unsigned int)__builtin_amdgcn_cvt_pk_fp8_f32(c, d, (int)q, true);
    return q;
#else
    union { unsigned int u; unsigned char cc[4]; } q;
    q.cc[0] = to_fp8(a); q.cc[1] = to_fp8(b); q.cc[2] = to_fp8(c); q.cc[3] = to_fp8(d);
    return q.u;
#endif
}

// ---------------- Kernel 1: normalize rows, emit fp8 z (k-interleaved), pos --
// Column permutation within each 64-block (row-independent): any fixed K-perm
// applied to BOTH MFMA operands cancels in the dot product.
__global__ __launch_bounds__(256) void norm_kernel(
    const float* __restrict__ p1, const float* __restrict__ p2,
    unsigned char* __restrict__ zq, float* __restrict__ pos)
{
    const int r = blockIdx.x;
    const int t = threadIdx.x;
    const float4 x1 = ((const float4*)(p1 + (size_t)r * DIM))[t];
    const float4 x2 = ((const float4*)(p2 + (size_t)r * DIM))[t];
    float s1  = x1.x*x1.x + x1.y*x1.y + x1.z*x1.z + x1.w*x1.w;
    float s2  = x2.x*x2.x + x2.y*x2.y + x2.z*x2.z + x2.w*x2.w;
    float s12 = x1.x*x2.x + x1.y*x2.y + x1.z*x2.z + x1.w*x2.w;
#pragma unroll
    for (int off = 1; off < 64; off <<= 1) {
        s1  += __shfl_xor(s1,  off);
        s2  += __shfl_xor(s2,  off);
        s12 += __shfl_xor(s12, off);
    }
    __shared__ float ls[3][4];
    const int wid = t >> 6;
    if ((t & 63) == 0) { ls[0][wid] = s1; ls[1][wid] = s2; ls[2][wid] = s12; }
    __syncthreads();
    s1  = ls[0][0] + ls[0][1] + ls[0][2] + ls[0][3];
    s2  = ls[1][0] + ls[1][1] + ls[1][2] + ls[1][3];
    s12 = ls[2][0] + ls[2][1] + ls[2][2] + ls[2][3];
    const float rn1 = 1.0f / fmaxf(sqrtf(s1), 1e-12f);
    const float rn2 = 1.0f / fmaxf(sqrtf(s2), 1e-12f);
    if (t == 0) pos[r] = s12 * rn1 * rn2;

    const int j0 = (t << 2) & 63;       // col within 64-block
    const int kb = t >> 4;              // 64-block index
    const int pb = (j0 < 32) ? (((j0 >> 3) << 4) + (j0 & 7))
                             : ((((j0 - 32) >> 3) << 4) + 8 + ((j0 - 32) & 7));
    const size_t off8 = (size_t)kb * 64 + pb;
    *(unsigned int*)(zq + (size_t)r * DIM + off8) =
        pk4_fp8(x1.x * rn1, x1.y * rn1, x1.z * rn1, x1.w * rn1);
    *(unsigned int*)(zq + (size_t)(NB + r) * DIM + off8) =
        pk4_fp8(x2.x * rn2, x2.y * rn2, x2.z * rn2, x2.w * rn2);
}

// ------- Kernel 2: 256x128 MX-fp8 symmetric z.z^T, mfma_scale 32x32x64 ------
// Tile (a,v): A rows [256a,+256), B cols [128v,+128), v>=2a. 8 waves (4x2),
// per-wave 64x64 via 2x2 quadrants of 32x32, acc f32x16 each. Scale=127
// (E8M0 => 1.0, exact). REGISTER BUDGET [measured R12-R14]: hipcc arch-VGPR
// budget = 256 / launch_bounds_arg2, independent of block size; mfma_scale
// accumulators are NOT placed in AGPRs (unlike plain mfma), so demand
// (~64 acc + ~24 ops + ~40 addr) needs arg2 = 1 -> 256-reg budget.
// (512,2)'s 128 budget spilled accs (R14: 635 MB scratch, MfmaUtil 4%).
__global__ __launch_bounds__(512, 1) void sim_kernel(
    const unsigned char* __restrict__ zq,
    float* __restrict__ partials,    // [N2][PS], zeroed before launch
    float* __restrict__ lup)         // [NJOBS]
{
    __shared__ __align__(16) unsigned char bufA[2][256 * 64]; // 32 KB
    __shared__ __align__(16) unsigned char bufB[2][128 * 64]; // 16 KB

    const int t    = threadIdx.x;
    const int lane = t & 63;
    const int wid  = t >> 6;       // 0..7
    const int wr   = wid >> 1;     // 0..3 (64-row strip of 256)
    const int wc   = wid & 1;      // 0..1 (64-col strip of 128)

    const int bid = blockIdx.x;
    const int job = (bid & 7) * (NJOBS / 8) + (bid >> 3);   // bijective XCD chunk
    int a = 0;                                   // start(a) = a*(65-a)
    while ((a + 1) * (64 - a) <= job) ++a;
    const int v = 2 * a + (job - a * (65 - a));
    const int row0 = a << 8;
    const int col0 = v << 7;

    const int colf = lane & 31;    // fragment row (A) / col (B) within 32
    const int hi   = lane >> 5;    // k-half 0/1
    const int rc   = (colf >> 1) & 3;                 // bank-swizzle row class
    const int sl0  = (((hi << 1) | 0) ^ rc) << 4;     // swizzled granule bytes
    const int sl1  = (((hi << 1) | 1) ^ rc) << 4;
    const int aO0  = ((wr << 6) + colf) << 6;         // quadrant m=0 row base
    const int aO1  = ((wr << 6) + 32 + colf) << 6;    // m=1
    const int bO0  = ((wc << 6) + colf) << 6;         // n=0
    const int bO1  = ((wc << 6) + 32 + colf) << 6;    // n=1

    // staging: 24 chunks of 16 rows x 64B (A: 0-15, B: 16-23), 3 per wave;
    // lane: row l>>2, LDS slot l&3, global granule (l&3)^((l>>3)&3) (involution)
    const int srow = lane >> 2;
    const int sgr  = (((lane & 3) ^ ((lane >> 3) & 3)) << 4);

#define STAGE(bsel, ktv) do { \
    _Pragma("unroll") \
    for (int c = 0; c < 3; ++c) { \
        const int ch  = wid * 3 + c; \
        const int isB = ch >> 4; \
        const int chl = ch & 15; \
        const unsigned char* src = zq + (size_t)((isB ? col0 : row0) + (chl << 4) + srow) * DIM \
                                      + (ktv) * 64 + sgr; \
        gload_lds16(src, (isB ? &bufB[bsel][chl << 10] : &bufA[bsel][chl << 10])); \
    } \
} while (0)

#define RD8(dst, base, off) do { \
    i32x4 lo_ = *(const i32x4*)((base) + (off) + sl0); \
    i32x4 hi_ = *(const i32x4*)((base) + (off) + sl1); \
    dst = __builtin_shufflevector(lo_, hi_, 0, 1, 2, 3, 4, 5, 6, 7); \
} while (0)

    f32x16 acc00 = {}, acc01 = {}, acc10 = {}, acc11 = {};

    STAGE(0, 0);
    __syncthreads();

#pragma unroll
    for (int kt = 0; kt < 16; ++kt) {
        const int cur = kt & 1;
        if (kt < 15) STAGE(cur ^ 1, kt + 1);
        const unsigned char* Ab = &bufA[cur][0];
        const unsigned char* Bb = &bufB[cur][0];
        i32x8 b0, b1, aq;
        RD8(b0, Bb, bO0); RD8(b1, Bb, bO1);
        RD8(aq, Ab, aO0);
        acc00 = __builtin_amdgcn_mfma_scale_f32_32x32x64_f8f6f4(aq, b0, acc00, 0, 0, 0, 127, 0, 127);
        acc01 = __builtin_amdgcn_mfma_scale_f32_32x32x64_f8f6f4(aq, b1, acc01, 0, 0, 0, 127, 0, 127);
        RD8(aq, Ab, aO1);
        acc10 = __builtin_amdgcn_mfma_scale_f32_32x32x64_f8f6f4(aq, b0, acc10, 0, 0, 0, 127, 0, 127);
        acc11 = __builtin_amdgcn_mfma_scale_f32_32x32x64_f8f6f4(aq, b1, acc11, 0, 0, 0, 127, 0, 127);
        __syncthreads();
    }
#undef RD8
#undef STAGE

    // ---- epilogue: 32x32 C/D layout col=lane&31, row=(reg&3)+8(reg>>2)+4hi --
    float* rsum2 = (float*)&bufA[0][0];     // [256][2] per-(row,wc)
    float* csum4 = rsum2 + 512;             // [128][4] per-(col,wr)
    float* lured = csum4 + 512;             // [8]

    const int  ur   = 2 * a + (wr >> 1);    // wave-uniform row unit
    const bool rowP = (ur <= v);
    const bool colP = (ur <  v);

    float lu = 0.0f;
    float cs[2] = {0.0f, 0.0f};
#pragma unroll
    for (int m = 0; m < 2; ++m) {
        const int rbase = row0 + (wr << 6) + (m << 5);
        const int rblk  = rbase >> 11;
        float rs[16] = {};
#pragma unroll
        for (int n = 0; n < 2; ++n) {
            const int  cbase = col0 + (wc << 6) + (n << 5);
            const bool dq    = (rbase == cbase);
            const bool inreg = ((cbase >> 11) == rblk) && (rblk < 2);
            const bool abv   = (cbase > rbase);
            const f32x16 d = m ? (n ? acc11 : acc10) : (n ? acc01 : acc00);
#pragma unroll
            for (int r = 0; r < 16; ++r) {
                const int rw = (r & 3) + ((r >> 2) << 3) + (hi << 2);
                const float s = d[r];
                float e = exp2f(14.4269504f * s);
                if (dq) e = (colf == rw) ? 0.0f : e;
                if (rowP) rs[r] += e;
                if (colP) cs[n] += e;
                if (inreg && (abv || (dq && (colf > rw)))) {
                    const float d2 = fmaxf(2.0f - 2.0f * s, 0.0f);
                    lu += exp2f(-2.88539008f * d2);
                }
            }
        }
#pragma unroll
        for (int off = 1; off < 32; off <<= 1) {
#pragma unroll
            for (int r = 0; r < 16; ++r) rs[r] += __shfl_xor(rs[r], off);
        }
        if (colf == 0) {
#pragma unroll
            for (int r = 0; r < 16; ++r) {
                const int rw = (r & 3) + ((r >> 2) << 3) + (hi << 2);
                rsum2[((wr << 6) + (m << 5) + rw) * 2 + wc] = rs[r];
            }
        }
    }
#pragma unroll
    for (int n = 0; n < 2; ++n) cs[n] += __shfl_xor(cs[n], 32);
    if (hi == 0) {
#pragma unroll
        for (int n = 0; n < 2; ++n)
            csum4[((wc << 6) + (n << 5) + colf) * 4 + wr] = cs[n];
    }
#pragma unroll
    for (int off = 1; off < 64; off <<= 1) lu += __shfl_xor(lu, off);
    if (lane == 0) lured[wid] = lu;
    __syncthreads();

    if (t == 0) {
        float s = 0.0f;
#pragma unroll
        for (int w = 0; w < 8; ++w) s += lured[w];
        lup[job] = s;
    }
    if (t < 256) {
        partials[(size_t)(row0 + t) * PS + v] = rsum2[t * 2] + rsum2[t * 2 + 1];
    } else if (t < 384) {
        const int j2 = t - 256;
        const float* p = csum4 + j2 * 4;
        partials[(size_t)(col0 + j2) * PS + 64 + a] = ((p[0] + p[1]) + p[2]) + p[3];
    }
}

// --------- Kernel 3a: per-row denom -> log, 128 rows per block --------------
__global__ __launch_bounds__(128) void logred_kernel(
    const float* __restrict__ partials, double* __restrict__ red_log)
{
    const int t   = threadIdx.x;
    const int row = blockIdx.x * 128 + t;
    const float* p = partials + (size_t)row * PS;
    float dsum = 0.0f;
#pragma unroll
    for (int i = 0; i < PS; ++i) dsum += p[i];
    double l = log((double)dsum);
    __shared__ double sd[128];
    sd[t] = l;
    __syncthreads();
    for (int s = 64; s > 0; s >>= 1) {
        if (t < s) sd[t] += sd[t + s];
        __syncthreads();
    }
    if (t == 0) red_log[blockIdx.x] = sd[0];
}

// --------- Kernel 3b: final scalars --------------------------------------
__global__ __launch_bounds__(256) void final_kernel(
    const double* __restrict__ red_log, const float* __restrict__ pos,
    const float* __restrict__ lup, float* __restrict__ out)
{
    const int t = threadIdx.x;
    double dlog = 0.0, dpos = 0.0, ds1 = 0.0, ds2 = 0.0;
    if (t < 64) dlog = red_log[t];
    for (int i = t; i < NB; i += 256) dpos += (double)pos[i];
    for (int i = t; i < NJOBS; i += 256) {
        int a = 0;
        while ((a + 1) * (64 - a) <= i) ++a;
        const int v = 2 * a + (i - a * (65 - a));
        const double val = (double)lup[i];
        if (a < 8 && v < 16) ds1 += val;                       // z_i[:2048] block
        else if (a >= 8 && a < 16 && v >= 16 && v < 32) ds2 += val; // z_i[2048:]
    }
    __shared__ double sd[4][256];
    sd[0][t] = dlog; sd[1][t] = dpos; sd[2][t] = ds1; sd[3][t] = ds2;
    __syncthreads();
    for (int s = 128; s > 0; s >>= 1) {
        if (t < s) {
            sd[0][t] += sd[0][t + s]; sd[1][t] += sd[1][t + s];
            sd[2][t] += sd[2][t + s]; sd[3][t] += sd[3][t + s];
        }
        __syncthreads();
    }
    if (t == 0) {
        const double mean_pos = sd[1][0] / (double)NB;
        const double loss   = sd[0][0] / (double)N2 - mean_pos * 10.0;   // /TEMP
        const double lalign = 2.0 - 2.0 * mean_pos;
        const double C      = 2048.0 * 2047.0 * 0.5;
        const double lunif  = 0.5 * (log(sd[2][0] / C) + log(sd[3][0] / C));
        out[0] = (float)loss;
        out[1] = (float)lalign;
        out[2] = (float)lunif;
    }
}

extern "C" void kernel_launch(void* const* d_in, const int* in_sizes, int n_in,
                              void* d_out, int out_size, void* d_ws, size_t ws_size,
                              hipStream_t stream) {
    const float* p1 = (const float*)d_in[0];
    const float* p2 = (const float*)d_in[1];
    float* out = (float*)d_out;

    char* ws = (char*)d_ws;
    unsigned char* zq = (unsigned char*)ws;                               // 8 MB
    float*  partials  = (float*)(ws + ((size_t)8 << 20));                 // 3 MB [8192][96]
    float*  pos       = (float*)(ws + ((size_t)12 << 20));                // 16 KB
    float*  lup       = (float*)(ws + ((size_t)12 << 20) + 16384);        // ~4.2 KB
    double* red_log   = (double*)(ws + ((size_t)12 << 20) + 24576);       // 512 B

    hipMemsetAsync(partials, 0, (size_t)N2 * PS * sizeof(float), stream);
    hipLaunchKernelGGL(norm_kernel,   dim3(NB),    dim3(256), 0, stream, p1, p2, zq, pos);
    hipLaunchKernelGGL(sim_kernel,    dim3(NJOBS), dim3(512), 0, stream, zq, partials, lup);
    hipLaunchKernelGGL(logred_kernel, dim3(64),    dim3(128), 0, stream, partials, red_log);
    hipLaunchKernelGGL(final_kernel,  dim3(1),     dim3(256), 0, stream, red_log, pos, lup, out);
}

// Round 16
// 89.444 us; speedup vs baseline: 6.3751x; 3.6398x over previous
//
#include <hip/hip_runtime.h>
#include <hip/hip_bf16.h>
#include <math.h>

#define DIM 1024
#define NB  4096      // B
#define N2  8192      // 2B
#define BT  256       // output tile dim
#define NT2 32        // N2 / BT
#define NTILES 528    // NT2*(NT2+1)/2 upper-triangular tiles

typedef int   i32x4 __attribute__((ext_vector_type(4)));

__device__ __forceinline__ void gload_lds16(const unsigned char* g, unsigned char* l) {
    __builtin_amdgcn_global_load_lds((__attribute__((address_space(1))) void*)(g),
                                     (__attribute__((address_space(3))) void*)(l),
                                     16, 0, 0);
}

// pack 4 int8 (round-to-nearest of x*127; |x|<=1 so no clamp needed)
__device__ __forceinline__ unsigned int pk4_i8(float a, float b, float c, float d) {
    const int ia = __float2int_rn(a * 127.0f), ib = __float2int_rn(b * 127.0f);
    const int ic = __float2int_rn(c * 127.0f), id = __float2int_rn(d * 127.0f);
    return (unsigned)(ia & 255) | ((unsigned)(ib & 255) << 8) |
           ((unsigned)(ic & 255) << 16) | ((unsigned)(id & 255) << 24);
}

// ---------------- Kernel 1: normalize rows, emit i8 z (k-interleaved), pos --
// Column permutation within each 64-block: global col j -> stored byte
//   j<32: (j>>3)*16 + (j&7);  j>=32: ((j-32)>>3)*16 + 8 + ((j-32)&7)
// One 16B granule = one mfma_i32_16x16x64_i8 operand; the permutation is a
// bijection on instruction-k applied to BOTH operands => cancels in the dot.
__global__ __launch_bounds__(256) void norm_kernel(
    const float* __restrict__ p1, const float* __restrict__ p2,
    unsigned char* __restrict__ zq, float* __restrict__ pos)
{
    const int r = blockIdx.x;
    const int t = threadIdx.x;
    const float4 x1 = ((const float4*)(p1 + (size_t)r * DIM))[t];
    const float4 x2 = ((const float4*)(p2 + (size_t)r * DIM))[t];
    float s1  = x1.x*x1.x + x1.y*x1.y + x1.z*x1.z + x1.w*x1.w;
    float s2  = x2.x*x2.x + x2.y*x2.y + x2.z*x2.z + x2.w*x2.w;
    float s12 = x1.x*x2.x + x1.y*x2.y + x1.z*x2.z + x1.w*x2.w;
#pragma unroll
    for (int off = 1; off < 64; off <<= 1) {
        s1  += __shfl_xor(s1,  off);
        s2  += __shfl_xor(s2,  off);
        s12 += __shfl_xor(s12, off);
    }
    __shared__ float ls[3][4];
    const int wid = t >> 6;
    if ((t & 63) == 0) { ls[0][wid] = s1; ls[1][wid] = s2; ls[2][wid] = s12; }
    __syncthreads();
    s1  = ls[0][0] + ls[0][1] + ls[0][2] + ls[0][3];
    s2  = ls[1][0] + ls[1][1] + ls[1][2] + ls[1][3];
    s12 = ls[2][0] + ls[2][1] + ls[2][2] + ls[2][3];
    const float rn1 = 1.0f / fmaxf(sqrtf(s1), 1e-12f);
    const float rn2 = 1.0f / fmaxf(sqrtf(s2), 1e-12f);
    if (t == 0) pos[r] = s12 * rn1 * rn2;

    const int j0 = (t << 2) & 63;       // col within 64-block
    const int kb = t >> 4;              // 64-block index
    const int pb = (j0 < 32) ? (((j0 >> 3) << 4) + (j0 & 7))
                             : ((((j0 - 32) >> 3) << 4) + 8 + ((j0 - 32) & 7));
    const size_t off8 = (size_t)kb * 64 + pb;
    *(unsigned int*)(zq + (size_t)r * DIM + off8) =
        pk4_i8(x1.x * rn1, x1.y * rn1, x1.z * rn1, x1.w * rn1);
    *(unsigned int*)(zq + (size_t)(NB + r) * DIM + off8) =
        pk4_i8(x2.x * rn2, x2.y * rn2, x2.z * rn2, x2.w * rn2);
}

// ------- Kernel 2: 256^2 i8 symmetric z.z^T, 16 waves (4x4), 64x64/wave -----
// R10 structure (best measured: sim 84.8us) with fp8->i8: one ds_read_b128
// granule feeds ONE mfma_i32_16x16x64_i8 (2x rate, half the instrs of fp8
// 16x16x32). Plain-MFMA acc -> AGPRs: 64 arch VGPR + 64 AGPR fits (1024,4)'s
// 128-unified budget exactly (R10-verified; mfma_scale variants spill, R13-15).
__global__ __launch_bounds__(1024, 4) void sim_kernel(
    const unsigned char* __restrict__ zq,
    float* __restrict__ partials,    // [N2][NT2]
    float* __restrict__ lup)         // [NT2*NT2], rt<=ct slots only
{
    __shared__ __align__(16) unsigned char buf[2][2][BT * 64]; // 64 KB
    const int t    = threadIdx.x;
    const int lane = t & 63;
    const int wid  = t >> 6;       // 0..15
    const int wr   = wid >> 2;     // 0..3 (64-row strip)
    const int wc   = wid & 3;      // 0..3 (64-col strip)

    const int bid = blockIdx.x;
    const int job = (bid & 7) * (NTILES / 8) + (bid >> 3);   // bijective XCD swizzle
    int rt = 0;
    while ((rt + 1) * NT2 - (((rt + 1) * rt) >> 1) <= job) ++rt;
    const int ct = rt + job - (rt * NT2 - ((rt * (rt - 1)) >> 1));
    const bool isdiag = (rt == ct);
    const int row0 = rt * BT;
    const int col0 = ct * BT;

    const int fr = lane & 15;      // fragment row (A) / col (B)
    const int kg = lane >> 4;      // k-group 0..3
    const int aoff = (((wr << 6) + fr) << 6) + (kg << 4);
    const int boff = (((wc << 6) + fr) << 6) + (kg << 4);
    const unsigned char* Ab[2] = { &buf[0][0][0] + aoff, &buf[1][0][0] + aoff };
    const unsigned char* Bb[2] = { &buf[0][1][0] + boff, &buf[1][1][0] + boff };

    // staging: wave w covers rows [16w,16w+16); lane: row 16w+(l>>2), granule l&3
    const int srow = (wid << 4) + (lane >> 2);
    const int sgr  = (lane & 3) << 4;
    const unsigned char* arow = zq + (size_t)(row0 + srow) * DIM + sgr;
    const unsigned char* bcol = zq + (size_t)(col0 + srow) * DIM + sgr;

    i32x4 acc[4][4] = {};

    // prologue: K-tile 0 -> buf0
    gload_lds16(arow, &buf[0][0][wid << 10]);
    gload_lds16(bcol, &buf[0][1][wid << 10]);
    __syncthreads();

#pragma unroll
    for (int kt = 0; kt < 16; ++kt) {
        const int cur = kt & 1;
        if (kt < 15) {
            gload_lds16(arow + (kt + 1) * 64, &buf[cur ^ 1][0][wid << 10]);
            gload_lds16(bcol + (kt + 1) * 64, &buf[cur ^ 1][1][wid << 10]);
        }
        i32x4 bq[4];
#pragma unroll
        for (int n = 0; n < 4; ++n)
            bq[n] = *(const i32x4*)(Bb[cur] + (n << 10));
#pragma unroll
        for (int m = 0; m < 4; ++m) {
            const i32x4 aq = *(const i32x4*)(Ab[cur] + (m << 10));
#pragma unroll
            for (int n = 0; n < 4; ++n)
                acc[m][n] = __builtin_amdgcn_mfma_i32_16x16x64_i8(aq, bq[n], acc[m][n], 0, 0, 0);
        }
        __syncthreads();
    }

    // ---- epilogue: C/D layout col=lane&15, row=(lane>>4)*4+reg ----
    float* rsum4 = (float*)&buf[0][0][0];   // [256][4] per-(row,wc) slots
    float* csum4 = rsum4 + 1024;            // [256][4] per-(col,wr) slots
    float* lured = csum4 + 1024;            // [16]

    const int  rsub  = (lane >> 4) << 2;
    const int  csub  = lane & 15;
    const bool inreg = (ct < 8) || (rt >= 8 && ct < 16);  // lunif sub-blocks
    const int  rbase = row0 + (wr << 6);
    const int  cbase = col0 + (wc << 6);
    const float inv = 1.0f / 16129.0f;      // 1/127^2

    float lu = 0.0f;
    float cs[4] = {0.0f, 0.0f, 0.0f, 0.0f};
#pragma unroll
    for (int m = 0; m < 4; ++m) {
        float rs[4] = {0.0f, 0.0f, 0.0f, 0.0f};
#pragma unroll
        for (int n = 0; n < 4; ++n) {
            const int gcol = cbase + (n << 4) + csub;
#pragma unroll
            for (int r = 0; r < 4; ++r) {
                const int grow = rbase + (m << 4) + rsub + r;
                const float s = (float)acc[m][n][r] * inv;
                float e = __expf(10.0f * s);
                if (isdiag) e = (grow != gcol) ? e : 0.0f;
                rs[r] += e;
                cs[n] += e;
                if (inreg && (!isdiag || gcol > grow)) {
                    const float d2 = fmaxf(2.0f - 2.0f * s, 0.0f);
                    lu += __expf(-2.0f * d2);
                }
            }
        }
#pragma unroll
        for (int off = 1; off < 16; off <<= 1) {
#pragma unroll
            for (int r = 0; r < 4; ++r) rs[r] += __shfl_xor(rs[r], off);
        }
        if ((lane & 15) == 0) {
#pragma unroll
            for (int r = 0; r < 4; ++r)
                rsum4[((wr << 6) + (m << 4) + rsub + r) * 4 + wc] = rs[r];
        }
    }
    if (!isdiag) {
#pragma unroll
        for (int off = 16; off < 64; off <<= 1) {
#pragma unroll
            for (int n = 0; n < 4; ++n) cs[n] += __shfl_xor(cs[n], off);
        }
        if (lane < 16) {
#pragma unroll
            for (int n = 0; n < 4; ++n)
                csum4[((wc << 6) + (n << 4) + lane) * 4 + wr] = cs[n];
        }
    }
#pragma unroll
    for (int off = 1; off < 64; off <<= 1) lu += __shfl_xor(lu, off);
    if (lane == 0) lured[wid] = lu;
    __syncthreads();

    if (t == 0) {
        float s = 0.0f;
#pragma unroll
        for (int w = 0; w < 16; ++w) s += lured[w];
        lup[rt * NT2 + ct] = s;
    }
    if (t < 256) {
        const float* p = rsum4 + t * 4;
        partials[(size_t)(row0 + t) * NT2 + ct] = ((p[0] + p[1]) + p[2]) + p[3];
    } else if (t < 512 && !isdiag) {
        const float* p = csum4 + (t - 256) * 4;
        partials[(size_t)(col0 + t - 256) * NT2 + rt] = ((p[0] + p[1]) + p[2]) + p[3];
    }
}

// --------- Kernel 3a: per-row denom -> log, 128 rows per block --------------
__global__ __launch_bounds__(128) void logred_kernel(
    const float* __restrict__ partials, double* __restrict__ red_log)
{
    const int t   = threadIdx.x;
    const int row = blockIdx.x * 128 + t;
    const float* p = partials + (size_t)row * NT2;
    float dsum = 0.0f;
#pragma unroll
    for (int i = 0; i < NT2; ++i) dsum += p[i];
    double l = log((double)dsum);
    __shared__ double sd[128];
    sd[t] = l;
    __syncthreads();
    for (int s = 64; s > 0; s >>= 1) {
        if (t < s) sd[t] += sd[t + s];
        __syncthreads();
    }
    if (t == 0) red_log[blockIdx.x] = sd[0];
}

// --------- Kernel 3b: final scalars --------------------------------------
__global__ __launch_bounds__(256) void final_kernel(
    const double* __restrict__ red_log, const float* __restrict__ pos,
    const float* __restrict__ lup, float* __restrict__ out)
{
    const int t = threadIdx.x;
    double dlog = 0.0, dpos = 0.0, ds1 = 0.0, ds2 = 0.0;
    if (t < 64) dlog = red_log[t];
    for (int i = t; i < NB; i += 256) dpos += (double)pos[i];
    for (int i = t; i < NT2 * NT2; i += 256) {
        const int rt = i >> 5, ct = i & 31;
        if (rt > ct) continue;                 // only upper-tri tiles written
        const double v = (double)lup[i];
        if (rt < 8 && ct < 8) ds1 += v;
        else if (rt >= 8 && rt < 16 && ct >= 8 && ct < 16) ds2 += v;
    }
    __shared__ double sd[4][256];
    sd[0][t] = dlog; sd[1][t] = dpos; sd[2][t] = ds1; sd[3][t] = ds2;
    __syncthreads();
    for (int s = 128; s > 0; s >>= 1) {
        if (t < s) {
            sd[0][t] += sd[0][t + s]; sd[1][t] += sd[1][t + s];
            sd[2][t] += sd[2][t + s]; sd[3][t] += sd[3][t + s];
        }
        __syncthreads();
    }
    if (t == 0) {
        const double mean_pos = sd[1][0] / (double)NB;
        const double loss   = sd[0][0] / (double)N2 - mean_pos * 10.0;   // /TEMP
        const double lalign = 2.0 - 2.0 * mean_pos;
        const double C      = 2048.0 * 2047.0 * 0.5;
        const double lunif  = 0.5 * (log(sd[2][0] / C) + log(sd[3][0] / C));
        out[0] = (float)loss;
        out[1] = (float)lalign;
        out[2] = (float)lunif;
    }
}

extern "C" void kernel_launch(void* const* d_in, const int* in_sizes, int n_in,
                              void* d_out, int out_size, void* d_ws, size_t ws_size,
                              hipStream_t stream) {
    const float* p1 = (const float*)d_in[0];
    const float* p2 = (const float*)d_in[1];
    float* out = (float*)d_out;

    char* ws = (char*)d_ws;
    unsigned char* zq = (unsigned char*)ws;                              // 8 MB
    float*  partials  = (float*)(ws + ((size_t)8 << 20));                // 1 MB [8192][32]
    float*  pos       = (float*)(ws + ((size_t)9 << 20));                // 16 KB
    float*  lup       = (float*)(ws + ((size_t)9 << 20) + 16384);        // 4 KB
    double* red_log   = (double*)(ws + ((size_t)9 << 20) + 16384 + 4096);// 512 B

    hipLaunchKernelGGL(norm_kernel,   dim3(NB),     dim3(256),  0, stream, p1, p2, zq, pos);
    hipLaunchKernelGGL(sim_kernel,    dim3(NTILES), dim3(1024), 0, stream, zq, partials, lup);
    hipLaunchKernelGGL(logred_kernel, dim3(64),     dim3(128),  0, stream, partials, red_log);
    hipLaunchKernelGGL(final_kernel,  dim3(1),      dim3(256),  0, stream, red_log, pos, lup, out);
}